// Round 8
// baseline (1818.747 us; speedup 1.0000x reference)
//
#include <hip/hip_runtime.h>
#include <hip/hip_bf16.h>

typedef __bf16 bf16x8 __attribute__((ext_vector_type(8)));
typedef __bf16 bf16x4v __attribute__((ext_vector_type(4)));
typedef float f32x4 __attribute__((ext_vector_type(4)));

#define MFMA(a, b, c) __builtin_amdgcn_mfma_f32_16x16x32_bf16((a), (b), (c), 0, 0, 0)
#define NEG_BIG (-1e30f)

// ---- LDS: 4 wave-private regions + block-wide exchange ------------------
// Per wave: q[64][36] | k[64][36] | vt[32][72] | odump[64][32];
// p[64][68] aliases q+k (4352 <= 4608). After both heads: barrier, then the
// whole block LDS is reused as the o-exchange xo[64][264] (16896 els).
#define QK_LD 36
#define VT_LD 72
#define P_LD 68
#define XO_LD 264
#define RQ 0
#define RK 2304
#define RV 4608
#define RP 0        // p aliases q+k
#define RD 6912     // o-dump for head 0: [64 lanes][32] bf16 = 2048 els
#define WREG 8960
#define TOTAL_ELS (4 * WREG)  // 35840 els = 71680 B -> 2 blocks/CU

static __device__ inline bf16x8 ld8x2(const __bf16* p) {
  bf16x4v lo = *(const bf16x4v*)p;
  bf16x4v hi = *(const bf16x4v*)(p + 4);
  bf16x8 r;
  r[0] = lo[0]; r[1] = lo[1]; r[2] = lo[2]; r[3] = lo[3];
  r[4] = hi[0]; r[5] = hi[1]; r[6] = hi[2]; r[7] = hi[3];
  return r;
}

// ---------------------------------------------------------------- prep -----
// Same packed layouts as round 7 (all verified):
//   wqkv_f[((h*6+nt)*8+k2)*64 + lane][0..8) ; q rows pre-scaled by 32^-0.5
//   wout_f[((ntile*8+kk)*64 + lane][0..8)
//   bias in C-fragment order [h][mt][nt][lane][r], -1e30 outside 49x49
__global__ __launch_bounds__(256) void prep_kernel(
    const float* __restrict__ w_qkv, const float* __restrict__ w_out,
    const float* __restrict__ rel_emb, const int* __restrict__ rel_idx,
    __bf16* __restrict__ wqkv_f, __bf16* __restrict__ wout_f,
    float* __restrict__ bias) {
  const float kScale = 0.17677669529663687f;
  int idx = blockIdx.x * 256 + threadIdx.x;
  if (idx < 24576) {
    int lane = idx & 63, k2 = (idx >> 6) & 7;
    int hn = idx >> 9;
    int nt = hn % 6, h = hn / 6;
    int quad = lane >> 4, l16 = lane & 15;
    int grow = (nt >> 1) * 256 + h * 32 + (nt & 1) * 16 + l16;
    const float* src = w_qkv + grow * 256 + k2 * 32 + quad * 8;
    float s = (nt < 2) ? kScale : 1.0f;
    bf16x8 d;
#pragma unroll
    for (int j = 0; j < 8; ++j) d[j] = (__bf16)(src[j] * s);
    *(bf16x8*)&wqkv_f[idx * 8] = d;
  } else if (idx < 32768) {
    int j2 = idx - 24576;
    int lane = j2 & 63, kk = (j2 >> 6) & 7, ntile = j2 >> 9;
    int quad = lane >> 4, l16 = lane & 15;
    const float* src = w_out + (ntile * 16 + l16) * 256 + kk * 32 + quad * 8;
    bf16x8 d;
#pragma unroll
    for (int j = 0; j < 8; ++j) d[j] = (__bf16)src[j];
    *(bf16x8*)&wout_f[j2 * 8] = d;
  } else if (idx < 65536) {
    int j = idx - 32768;
    int h = j >> 12;
    int mt = (j >> 10) & 3;
    int nt = (j >> 8) & 3;
    int lane = (j >> 2) & 63;
    int r = j & 3;
    int row = mt * 16 + ((lane >> 4) << 2) + r;
    int col = nt * 16 + (lane & 15);
    float v = NEG_BIG;
    if (row < 49 && col < 49) v = rel_emb[rel_idx[row * 49 + col] * 8 + h];
    bias[j] = v;
  }
}

// ---------------------------------------------------------------- main -----
// One block per window, 4 waves. Wave w owns heads {w, w+4} END-TO-END:
// qkv GEMM (full 64x96), q.kT, softmax, PV — all in wave-private LDS with
// ZERO barriers (lgkmcnt orders in-wave LDS). Only the out-projection needs
// cross-wave data: 2 barriers total (vs 15 in round 7). Each wave loads only
// its own heads' packed W-frags -> wqkv L2 traffic drops 4x. 8 independent
// wave-streams/CU (2 blocks x 4 waves) replace 4 lockstep block-streams.
// Register phases keep peak ~130: head-0 output is dumped to private LDS
// (RD) so it is NOT live through head 1; A-frags reloaded per k2.
// MFMA 16x16x32 bf16 layouts (HW-verified):
//   A: m=lane&15, k=quad*8+j   B: n=lane&15, k=quad*8+j
//   C/D: col=lane&15, row=quad*4+reg
__global__ __launch_bounds__(256, 2) void attn_kernel(
    const float* __restrict__ x, const __bf16* __restrict__ wqkv,
    const __bf16* __restrict__ wout, const float* __restrict__ bias,
    float* __restrict__ out) {
  __shared__ __attribute__((aligned(16))) __bf16 sm[TOTAL_ELS];

  const int tid = threadIdx.x;
  const int wave = tid >> 6;
  const int lane = tid & 63;
  const int quad = lane >> 4;
  const int l16 = lane & 15;

  const f32x4 fzero = {0.f, 0.f, 0.f, 0.f};
  __bf16* mw = sm + wave * WREG;
  const float* xg = x + (size_t)blockIdx.x * 12544;

  f32x4 oa1[4][2];  // head-1 PV output, lives only until the exchange

#pragma unroll
  for (int hh = 0; hh < 2; ++hh) {
    const int h = wave + hh * 4;
    const __bf16* wb = wqkv + (size_t)h * 24576;

    // ---- qkv: C(64x96) = x(64x256) @ Wh^T — whole head in one wave.
    // A-frags from global x per k2 (fp32->bf16 in regs); B-frags from the
    // packed stream (coalesced 1KB/wave, L2-hot, loaded by ONE wave only).
    f32x4 acc[4][6];
#pragma unroll
    for (int mt = 0; mt < 4; ++mt)
#pragma unroll
      for (int nt = 0; nt < 6; ++nt) acc[mt][nt] = fzero;

#pragma unroll
    for (int k2 = 0; k2 < 8; ++k2) {
      bf16x8 a[4];
#pragma unroll
      for (int mt = 0; mt < 4; ++mt) {
        // mt==3 covers rows 48..63: row 48 for all lanes (valid for l16=0,
        // clamped garbage for the rest; masked by bias / store guard).
        const int row = (mt == 3) ? 48 : (mt * 16 + l16);
        const float* xp = xg + row * 256 + k2 * 32 + quad * 8;
        float4 v0 = *(const float4*)xp;
        float4 v1 = *(const float4*)(xp + 4);
        bf16x8 t;
        t[0] = (__bf16)v0.x; t[1] = (__bf16)v0.y; t[2] = (__bf16)v0.z; t[3] = (__bf16)v0.w;
        t[4] = (__bf16)v1.x; t[5] = (__bf16)v1.y; t[6] = (__bf16)v1.z; t[7] = (__bf16)v1.w;
        a[mt] = t;
      }
#pragma unroll
      for (int nt = 0; nt < 6; ++nt) {
        bf16x8 b = *(const bf16x8*)&wb[(nt * 8 + k2) * 512 + lane * 8];
#pragma unroll
        for (int mt = 0; mt < 4; ++mt) acc[mt][nt] = MFMA(a[mt], b, acc[mt][nt]);
      }
    }

    // ---- scatter q,k row-major and v transposed — wave-private, no barrier
#pragma unroll
    for (int mt = 0; mt < 4; ++mt) {
      const int rb = mt * 16 + quad * 4;
#pragma unroll
      for (int t = 0; t < 2; ++t) {
#pragma unroll
        for (int r = 0; r < 4; ++r) {
          mw[RQ + (rb + r) * QK_LD + t * 16 + l16] = (__bf16)acc[mt][t][r];
          mw[RK + (rb + r) * QK_LD + t * 16 + l16] = (__bf16)acc[mt][2 + t][r];
        }
        bf16x4v pv;
#pragma unroll
        for (int r = 0; r < 4; ++r) pv[r] = (__bf16)acc[mt][4 + t][r];
        *(bf16x4v*)&mw[RV + (t * 16 + l16) * VT_LD + rb] = pv;
      }
    }

    // ---- sim = q.kT + bias (full 64x64 per wave; bias in C-frag order)
    f32x4 sim[4][4];
    const float* bb = bias + (h << 12) + (lane << 2);
#pragma unroll
    for (int mt = 0; mt < 4; ++mt)
#pragma unroll
      for (int nt = 0; nt < 4; ++nt)
        sim[mt][nt] = *(const f32x4*)&bb[(mt * 4 + nt) << 8];

    bf16x8 aq[4];
#pragma unroll
    for (int mt = 0; mt < 4; ++mt)
      aq[mt] = ld8x2(&mw[RQ + (mt * 16 + l16) * QK_LD + quad * 8]);
#pragma unroll
    for (int nt = 0; nt < 4; ++nt) {
      bf16x8 bk = ld8x2(&mw[RK + (nt * 16 + l16) * QK_LD + quad * 8]);
#pragma unroll
      for (int mt = 0; mt < 4; ++mt) sim[mt][nt] = MFMA(aq[mt], bk, sim[mt][nt]);
    }

    // ---- softmax, no max-subtraction (sim ~ N(0,1)-scale; -1e30 masks)
#pragma unroll
    for (int mt = 0; mt < 4; ++mt) {
      const int rb = mt * 16 + quad * 4;
#pragma unroll
      for (int r = 0; r < 4; ++r) {
        float e0 = __expf(sim[mt][0][r]), e1 = __expf(sim[mt][1][r]);
        float e2 = __expf(sim[mt][2][r]), e3 = __expf(sim[mt][3][r]);
        float sum = e0 + e1 + e2 + e3;
        sum += __shfl_xor(sum, 1);
        sum += __shfl_xor(sum, 2);
        sum += __shfl_xor(sum, 4);
        sum += __shfl_xor(sum, 8);
        float rs = (sum > 0.f) ? (1.0f / sum) : 0.f;
        const int row = rb + r;
        mw[RP + row * P_LD + l16] = (__bf16)(e0 * rs);
        mw[RP + row * P_LD + 16 + l16] = (__bf16)(e1 * rs);
        mw[RP + row * P_LD + 32 + l16] = (__bf16)(e2 * rs);
        mw[RP + row * P_LD + 48 + l16] = (__bf16)(e3 * rs);
      }
    }

    // ---- PV: o_h(64x32) = P(64x64) @ V(64x32)
    f32x4 po[4][2];
#pragma unroll
    for (int mt = 0; mt < 4; ++mt) {
      po[mt][0] = fzero;
      po[mt][1] = fzero;
    }
#pragma unroll
    for (int kk = 0; kk < 2; ++kk) {
      bf16x8 bv[2];
#pragma unroll
      for (int t = 0; t < 2; ++t)
        bv[t] = *(const bf16x8*)&mw[RV + (t * 16 + l16) * VT_LD + kk * 32 + quad * 8];
#pragma unroll
      for (int mt = 0; mt < 4; ++mt) {
        bf16x8 ap = ld8x2(&mw[RP + (mt * 16 + l16) * P_LD + kk * 32 + quad * 8]);
#pragma unroll
        for (int t = 0; t < 2; ++t) po[mt][t] = MFMA(ap, bv[t], po[mt][t]);
      }
    }

    if (hh == 0) {
      // dump head-0 o to private LDS so it is NOT live through head 1
      // layout: [lane][mt][t][r] bf16 -> 32 els/lane
#pragma unroll
      for (int mt = 0; mt < 4; ++mt)
#pragma unroll
        for (int t = 0; t < 2; ++t) {
          bf16x4v d;
#pragma unroll
          for (int r = 0; r < 4; ++r) d[r] = (__bf16)po[mt][t][r];
          *(bf16x4v*)&mw[RD + lane * 32 + mt * 8 + t * 4] = d;
        }
    } else {
#pragma unroll
      for (int mt = 0; mt < 4; ++mt)
#pragma unroll
        for (int t = 0; t < 2; ++t) oa1[mt][t] = po[mt][t];
    }
  }

  // ---- o exchange: reload head-0 dump (private read), then rebuild the
  // block-wide o matrix xo[64][264] over the whole LDS space.
  bf16x8 or0[4];
#pragma unroll
  for (int mt = 0; mt < 4; ++mt)
    or0[mt] = *(const bf16x8*)&mw[RD + lane * 32 + mt * 8];
  __syncthreads();  // B1: all waves done with private regions
#pragma unroll
  for (int mt = 0; mt < 4; ++mt) {
    const int rb = mt * 16 + quad * 4;
#pragma unroll
    for (int t = 0; t < 2; ++t)
#pragma unroll
      for (int r = 0; r < 4; ++r) {
        sm[(rb + r) * XO_LD + wave * 32 + t * 16 + l16] = or0[mt][t * 4 + r];
        sm[(rb + r) * XO_LD + (wave + 4) * 32 + t * 16 + l16] =
            (__bf16)oa1[mt][t][r];
      }
  }
  __syncthreads();  // B2: xo visible

  // ---- out projection: out(64x256) = o @ w_out^T (rows split by wave)
  const int am = wave * 16 + l16;
  const int i0 = wave * 16 + quad * 4;
  bf16x8 ofr[8];
#pragma unroll
  for (int k8 = 0; k8 < 8; ++k8)
    ofr[k8] = ld8x2(&sm[am * XO_LD + k8 * 32 + quad * 8]);

  float* ob_base = out + (size_t)blockIdx.x * 12544;
  for (int ct = 0; ct < 8; ++ct) {
    f32x4 fa[2];
    fa[0] = fzero;
    fa[1] = fzero;
#pragma unroll
    for (int kk = 0; kk < 8; ++kk) {
#pragma unroll
      for (int t = 0; t < 2; ++t) {
        bf16x8 bw = *(const bf16x8*)&wout[((ct * 2 + t) * 8 + kk) * 512 + lane * 8];
        fa[t] = MFMA(ofr[kk], bw, fa[t]);
      }
    }
    float* ob = ob_base + ct * 32;
#pragma unroll
    for (int t = 0; t < 2; ++t)
#pragma unroll
      for (int r = 0; r < 4; ++r) {
        const int row = i0 + r;
        if (row < 49) ob[row * 256 + t * 16 + l16] = fa[t][r];
      }
  }
}

// ---------------------------------------------------------------- launch ---
extern "C" void kernel_launch(void* const* d_in, const int* in_sizes, int n_in,
                              void* d_out, int out_size, void* d_ws, size_t ws_size,
                              hipStream_t stream) {
  (void)in_sizes; (void)n_in; (void)out_size; (void)ws_size;
  const float* x = (const float*)d_in[0];
  const float* w_qkv = (const float*)d_in[1];
  const float* w_out = (const float*)d_in[2];
  const float* rel_emb = (const float*)d_in[3];
  const int* rel_idx = (const int*)d_in[4];
  float* out = (float*)d_out;

  char* ws = (char*)d_ws;
  __bf16* wqkv_f = (__bf16*)ws;             // 768*256*2 = 393216 B
  __bf16* wout_f = (__bf16*)(ws + 393216);  // 256*256*2 = 131072 B
  float* bias = (float*)(ws + 524288);      // 131072 B

  prep_kernel<<<256, 256, 0, stream>>>(w_qkv, w_out, rel_emb, rel_idx,
                                       wqkv_f, wout_f, bias);
  attn_kernel<<<4096, 256, 0, stream>>>(x, wqkv_f, wout_f, bias, out);
}

// Round 9
// 903.956 us; speedup vs baseline: 2.0120x; 2.0120x over previous
//
#include <hip/hip_runtime.h>
#include <hip/hip_bf16.h>

typedef __bf16 bf16x8 __attribute__((ext_vector_type(8)));
typedef __bf16 bf16x4v __attribute__((ext_vector_type(4)));
typedef float f32x4 __attribute__((ext_vector_type(4)));

#define MFMA(a, b, c) __builtin_amdgcn_mfma_f32_16x16x32_bf16((a), (b), (c), 0, 0, 0)
#define NEG_BIG (-1e30f)

// ---- attn kernel LDS ------------------------------------------------------
// q single (wave-private rows), k/vt DOUBLE-buffered (cross-wave, alternate
// heads -> 1 barrier/head), p single (wave-private rows).
// 15872 els = 31744 B -> 5 blocks/CU at __launch_bounds__(256,5).
#define QK_LD 36
#define VT_LD 72
#define P_LD 68
#define RQ 0
#define RK0 2304
#define RK1 4608
#define RV0 6912
#define RV1 9216
#define RP 11520
#define TOTAL1 15872

// proj kernel LDS: o staged [64][264] = 33792 B -> 4 blocks/CU
#define XO_LD 264

static __device__ inline bf16x8 ld8x2(const __bf16* p) {
  bf16x4v lo = *(const bf16x4v*)p;
  bf16x4v hi = *(const bf16x4v*)(p + 4);
  bf16x8 r;
  r[0] = lo[0]; r[1] = lo[1]; r[2] = lo[2]; r[3] = lo[3];
  r[4] = hi[0]; r[5] = hi[1]; r[6] = hi[2]; r[7] = hi[3];
  return r;
}

// ---------------------------------------------------------------- prep -----
// Packed layouts (verified rounds 3-7):
//   wqkv_f[((h*6+nt)*8+k2)*64 + lane][0..8) ; q rows pre-scaled by 32^-0.5
//   wout_f[((ntile*8+kk)*64 + lane][0..8)
//   bias in C-fragment order [h][mt][nt][lane][r], -1e30 outside 49x49
__global__ __launch_bounds__(256) void prep_kernel(
    const float* __restrict__ w_qkv, const float* __restrict__ w_out,
    const float* __restrict__ rel_emb, const int* __restrict__ rel_idx,
    __bf16* __restrict__ wqkv_f, __bf16* __restrict__ wout_f,
    float* __restrict__ bias) {
  const float kScale = 0.17677669529663687f;
  int idx = blockIdx.x * 256 + threadIdx.x;
  if (idx < 24576) {
    int lane = idx & 63, k2 = (idx >> 6) & 7;
    int hn = idx >> 9;
    int nt = hn % 6, h = hn / 6;
    int quad = lane >> 4, l16 = lane & 15;
    int grow = (nt >> 1) * 256 + h * 32 + (nt & 1) * 16 + l16;
    const float* src = w_qkv + grow * 256 + k2 * 32 + quad * 8;
    float s = (nt < 2) ? kScale : 1.0f;
    bf16x8 d;
#pragma unroll
    for (int j = 0; j < 8; ++j) d[j] = (__bf16)(src[j] * s);
    *(bf16x8*)&wqkv_f[idx * 8] = d;
  } else if (idx < 32768) {
    int j2 = idx - 24576;
    int lane = j2 & 63, kk = (j2 >> 6) & 7, ntile = j2 >> 9;
    int quad = lane >> 4, l16 = lane & 15;
    const float* src = w_out + (ntile * 16 + l16) * 256 + kk * 32 + quad * 8;
    bf16x8 d;
#pragma unroll
    for (int j = 0; j < 8; ++j) d[j] = (__bf16)src[j];
    *(bf16x8*)&wout_f[j2 * 8] = d;
  } else if (idx < 65536) {
    int j = idx - 32768;
    int h = j >> 12;
    int mt = (j >> 10) & 3;
    int nt = (j >> 8) & 3;
    int lane = (j >> 2) & 63;
    int r = j & 3;
    int row = mt * 16 + ((lane >> 4) << 2) + r;
    int col = nt * 16 + (lane & 15);
    float v = NEG_BIG;
    if (row < 49 && col < 49) v = rel_emb[rel_idx[row * 49 + col] * 8 + h];
    bias[j] = v;
  }
}

// ---------------------------------------------------------------- attn -----
// Round-7 cooperative structure (4 waves, wave owns 16 rows) with:
//  * out-projection REMOVED (o written as bf16 into the window's own out
//    region; proj_kernel finishes it) -> no ofr, no otr round trip
//  * k/vt double-buffered -> ONE barrier per head (8 total)
//  * __launch_bounds__(256,5): demand ~75 < budget 102, 5 blocks/CU
// MFMA 16x16x32 bf16 layouts (HW-verified):
//   A: m=lane&15, k=quad*8+j   B: n=lane&15, k=quad*8+j
//   C/D: col=lane&15, row=quad*4+reg
__global__ __launch_bounds__(256, 5) void attn_kernel(
    const float* __restrict__ x, const __bf16* __restrict__ wqkv,
    const float* __restrict__ bias, float* __restrict__ out) {
  __shared__ __attribute__((aligned(16))) __bf16 sm[TOTAL1];

  const int tid = threadIdx.x;
  const int wave = tid >> 6;
  const int lane = tid & 63;
  const int quad = lane >> 4;
  const int l16 = lane & 15;
  const int i0 = wave * 16 + quad * 4;  // C/D row base
  const int am = wave * 16 + l16;       // A/B operand row

  const f32x4 fzero = {0.f, 0.f, 0.f, 0.f};

  // A-fragments straight from global x (fp32 -> bf16 in regs); rows 49..63
  // clamp to row 48 (garbage masked by bias / store guard).
  bf16x8 afr[8];
  {
    const float* xrow =
        x + (size_t)blockIdx.x * 12544 + (am > 48 ? 48 : am) * 256;
#pragma unroll
    for (int k2 = 0; k2 < 8; ++k2) {
      const float* xp = xrow + k2 * 32 + quad * 8;
      float4 v0 = *(const float4*)xp;
      float4 v1 = *(const float4*)(xp + 4);
      bf16x8 a;
      a[0] = (__bf16)v0.x; a[1] = (__bf16)v0.y; a[2] = (__bf16)v0.z; a[3] = (__bf16)v0.w;
      a[4] = (__bf16)v1.x; a[5] = (__bf16)v1.y; a[6] = (__bf16)v1.z; a[7] = (__bf16)v1.w;
      afr[k2] = a;
    }
  }

  // o destination: bf16 rows packed into this window's own out region
  // (49*256*2 B = 25088 <= 50176 B slot; proj_kernel stages before overwrite)
  __bf16* ob = (__bf16*)(out + (size_t)blockIdx.x * 12544);

#pragma unroll
  for (int h = 0; h < 8; ++h) {
    const int kb = (h & 1) ? RK1 : RK0;
    const int vb = (h & 1) ? RV1 : RV0;

    // qkv: C(64x96) = x(64x256) @ Wh^T, B-frags from packed global
    f32x4 acc[6];
#pragma unroll
    for (int t = 0; t < 6; ++t) acc[t] = fzero;
    {
      const __bf16* wb = wqkv + (size_t)h * 24576;
#pragma unroll
      for (int k2 = 0; k2 < 8; ++k2) {
        bf16x8 a = afr[k2];
#pragma unroll
        for (int nt = 0; nt < 6; ++nt) {
          bf16x8 b = *(const bf16x8*)&wb[(nt * 8 + k2) * 512 + lane * 8];
          acc[nt] = MFMA(a, b, acc[nt]);
        }
      }
    }

    // scatter q (single buf) and k/vt (alternating buf — the PREVIOUS
    // barrier guarantees everyone is done reading this buffer, head h-2)
#pragma unroll
    for (int t = 0; t < 2; ++t) {
#pragma unroll
      for (int r = 0; r < 4; ++r) {
        sm[RQ + (i0 + r) * QK_LD + t * 16 + l16] = (__bf16)acc[t][r];
        sm[kb + (i0 + r) * QK_LD + t * 16 + l16] = (__bf16)acc[2 + t][r];
      }
      bf16x4v pv;
#pragma unroll
      for (int r = 0; r < 4; ++r) pv[r] = (__bf16)acc[4 + t][r];
      *(bf16x4v*)&sm[vb + (t * 16 + l16) * VT_LD + i0] = pv;
    }

    // bias prefetch (C-fragment order), overlaps the barrier wait
    f32x4 sim[4];
    {
      const float* bb = bias + (h << 12) + (wave << 10) + (lane << 2);
#pragma unroll
      for (int nt = 0; nt < 4; ++nt) sim[nt] = *(const f32x4*)&bb[nt << 8];
    }
    __syncthreads();  // k/vt of head h visible (the ONLY barrier per head)

    // sim = q.k^T + bias
    {
      bf16x8 a = ld8x2(&sm[RQ + am * QK_LD + quad * 8]);
#pragma unroll
      for (int nt = 0; nt < 4; ++nt) {
        bf16x8 b = ld8x2(&sm[kb + (nt * 16 + l16) * QK_LD + quad * 8]);
        sim[nt] = MFMA(a, b, sim[nt]);
      }
    }

    // softmax, no max-subtraction (sim ~ N(0,1)-scale; -1e30 masks pads)
#pragma unroll
    for (int r = 0; r < 4; ++r) {
      float e0 = __expf(sim[0][r]), e1 = __expf(sim[1][r]);
      float e2 = __expf(sim[2][r]), e3 = __expf(sim[3][r]);
      float sum = e0 + e1 + e2 + e3;
      sum += __shfl_xor(sum, 1);
      sum += __shfl_xor(sum, 2);
      sum += __shfl_xor(sum, 4);
      sum += __shfl_xor(sum, 8);
      float rs = (sum > 0.f) ? (1.0f / sum) : 0.f;
      int row = i0 + r;
      sm[RP + row * P_LD + l16] = (__bf16)(e0 * rs);
      sm[RP + row * P_LD + 16 + l16] = (__bf16)(e1 * rs);
      sm[RP + row * P_LD + 32 + l16] = (__bf16)(e2 * rs);
      sm[RP + row * P_LD + 48 + l16] = (__bf16)(e3 * rs);
    }
    // p wave-private: in-wave LDS ordering suffices

    // o_h = P(64x64) @ V(64x32)
    f32x4 oa[2];
    oa[0] = fzero;
    oa[1] = fzero;
#pragma unroll
    for (int kk = 0; kk < 2; ++kk) {
      bf16x8 a = ld8x2(&sm[RP + am * P_LD + kk * 32 + quad * 8]);
#pragma unroll
      for (int t = 0; t < 2; ++t) {
        bf16x8 b = *(const bf16x8*)&sm[vb + (t * 16 + l16) * VT_LD + kk * 32 + quad * 8];
        oa[t] = MFMA(a, b, oa[t]);
      }
    }

    // store o (C-layout scatter, bf16): row i0+r, col h*32 + t*16 + l16
#pragma unroll
    for (int t = 0; t < 2; ++t)
#pragma unroll
      for (int r = 0; r < 4; ++r) {
        int row = i0 + r;
        if (row < 49) ob[row * 256 + h * 32 + t * 16 + l16] = (__bf16)oa[t][r];
      }
  }
}

// ---------------------------------------------------------------- proj -----
// out(49x256) = o(49x256) @ w_out^T per window, in place: stage bf16 o into
// LDS (all reads precede the barrier), then MFMA with packed wout and
// overwrite the region with fp32.
__global__ __launch_bounds__(256, 4) void proj_kernel(
    const __bf16* __restrict__ wout, float* __restrict__ out) {
  __shared__ __attribute__((aligned(16))) __bf16 so[64 * XO_LD];

  const int tid = threadIdx.x;
  const int wave = tid >> 6;
  const int lane = tid & 63;
  const int quad = lane >> 4;
  const int l16 = lane & 15;
  const int i0 = wave * 16 + quad * 4;
  const int am = wave * 16 + l16;

  const f32x4 fzero = {0.f, 0.f, 0.f, 0.f};
  float* outw = out + (size_t)blockIdx.x * 12544;
  const __bf16* ob = (const __bf16*)outw;

  // stage o rows 0..48 (bf16x8 coalesced), zero rows 49..63
  for (int i = tid; i < 1568; i += 256) {
    int row = i >> 5, c = (i & 31) * 8;
    *(bf16x8*)&so[row * XO_LD + c] = *(const bf16x8*)&ob[row * 256 + c];
  }
  {
    bf16x8 z;
#pragma unroll
    for (int j = 0; j < 8; ++j) z[j] = (__bf16)0.0f;
    for (int i = tid; i < 480; i += 256) {
      int row = 49 + (i >> 5), c = (i & 31) * 8;
      *(bf16x8*)&so[row * XO_LD + c] = z;
    }
  }
  __syncthreads();  // all global o reads done; safe to overwrite below

  bf16x8 ofr[8];
#pragma unroll
  for (int k8 = 0; k8 < 8; ++k8)
    ofr[k8] = ld8x2(&so[am * XO_LD + k8 * 32 + quad * 8]);

  for (int ct = 0; ct < 8; ++ct) {
    f32x4 fa[2];
    fa[0] = fzero;
    fa[1] = fzero;
#pragma unroll
    for (int kk = 0; kk < 8; ++kk) {
#pragma unroll
      for (int t = 0; t < 2; ++t) {
        bf16x8 bw = *(const bf16x8*)&wout[((ct * 2 + t) * 8 + kk) * 512 + lane * 8];
        fa[t] = MFMA(ofr[kk], bw, fa[t]);
      }
    }
    float* oc = outw + ct * 32;
#pragma unroll
    for (int t = 0; t < 2; ++t)
#pragma unroll
      for (int r = 0; r < 4; ++r) {
        int row = i0 + r;
        if (row < 49) oc[row * 256 + t * 16 + l16] = fa[t][r];
      }
  }
}

// ---------------------------------------------------------------- launch ---
extern "C" void kernel_launch(void* const* d_in, const int* in_sizes, int n_in,
                              void* d_out, int out_size, void* d_ws, size_t ws_size,
                              hipStream_t stream) {
  (void)in_sizes; (void)n_in; (void)out_size; (void)ws_size;
  const float* x = (const float*)d_in[0];
  const float* w_qkv = (const float*)d_in[1];
  const float* w_out = (const float*)d_in[2];
  const float* rel_emb = (const float*)d_in[3];
  const int* rel_idx = (const int*)d_in[4];
  float* out = (float*)d_out;

  char* ws = (char*)d_ws;
  __bf16* wqkv_f = (__bf16*)ws;             // 768*256*2 = 393216 B
  __bf16* wout_f = (__bf16*)(ws + 393216);  // 256*256*2 = 131072 B
  float* bias = (float*)(ws + 524288);      // 131072 B

  prep_kernel<<<256, 256, 0, stream>>>(w_qkv, w_out, rel_emb, rel_idx,
                                       wqkv_f, wout_f, bias);
  attn_kernel<<<4096, 256, 0, stream>>>(x, wqkv_f, bias, out);
  proj_kernel<<<4096, 256, 0, stream>>>(wout_f, out);
}